// Round 11
// baseline (177.579 us; speedup 1.0000x reference)
//
#include <hip/hip_runtime.h>
#include <hip/hip_bf16.h>

#define B_ 4
#define N_ 4096
#define D_ 128
#define KSEG 8
#define QSEG 8

typedef __bf16 bf16x8 __attribute__((ext_vector_type(8)));
typedef float f32x4 __attribute__((ext_vector_type(4)));
typedef _Float16 f16x4 __attribute__((ext_vector_type(4)));

// alpha = log2(e) / sqrt(128), folded into Qp at conversion time
#define ALPHA 0.12752361680972262f

// ws layout (fragment-linear packed, 16 B per (tile,frag,lane) chunk):
//   Qp : bf16 [B][256 qstep][4 f][64 lane][8]   @ 0      (4 MiB, alpha-scaled)
//   Kp : bf16 [B][128 kb][8 slot=f*2+ab][64][8] @ 4 MiB  (permuted-key frag order)
//   Vp : bf16 [B][128 kb][8 ds][64][8]          @ 8 MiB  (1/l folded in place)
//   l    : f32  [B][N]                          @ 12 MiB
//   part : f16 [KSEG=8][B][N][D]                @ 13 MiB (32 MiB -> ws = proven 45 MB)
#define OFF_KP   (4u << 20)
#define OFF_VP   (8u << 20)
#define OFF_L    (12u << 20)
#define OFF_PART (13u << 20)

// ---------------------------------------------------------------------------
// Kernel A: pack Q*alpha, K (permuted key order), V-transpose into fragment-
// linear layouts; last block zeroes l (replaces the memset dispatch).
// ---------------------------------------------------------------------------
__global__ __launch_bounds__(256) void cvt_kernel(
    const float* __restrict__ q, const float* __restrict__ k,
    const float* __restrict__ v,
    __bf16* __restrict__ qp, __bf16* __restrict__ kp, __bf16* __restrict__ vp,
    float* __restrict__ l)
{
    __shared__ float vl[32 * 129];   // 16.5 KiB (V section only)

    int bid = blockIdx.x;
    int tid = threadIdx.x;
    if (bid < 2048) {
        int g = (bid & 1023) * 256 + tid;   // 0..262143 within section
        int lane = g & 63;
        int l15 = lane & 15, quad = lane >> 4;
        if (bid < 1024) {
            int f = (g >> 6) & 3;
            int qstep = (g >> 8) & 255;
            int b = g >> 16;
            const float* src = q + ((size_t)(b * N_ + qstep * 16 + l15) * D_ + (f * 4 + quad) * 8);
            float4 x0 = *(const float4*)src;
            float4 x1 = *(const float4*)(src + 4);
            bf16x8 y;
            y[0] = (__bf16)(x0.x * ALPHA); y[1] = (__bf16)(x0.y * ALPHA);
            y[2] = (__bf16)(x0.z * ALPHA); y[3] = (__bf16)(x0.w * ALPHA);
            y[4] = (__bf16)(x1.x * ALPHA); y[5] = (__bf16)(x1.y * ALPHA);
            y[6] = (__bf16)(x1.z * ALPHA); y[7] = (__bf16)(x1.w * ALPHA);
            ((bf16x8*)qp)[g] = y;
        } else {
            int slot = (g >> 6) & 7;
            int kb = (g >> 9) & 127;
            int b = g >> 16;
            int f = slot >> 1, ab = slot & 1;
            int row = kb * 32 + (l15 >> 2) * 8 + (l15 & 3) + ab * 4;
            const float* src = k + ((size_t)(b * N_ + row) * D_ + (f * 4 + quad) * 8);
            float4 x0 = *(const float4*)src;
            float4 x1 = *(const float4*)(src + 4);
            bf16x8 y;
            y[0] = (__bf16)x0.x; y[1] = (__bf16)x0.y; y[2] = (__bf16)x0.z; y[3] = (__bf16)x0.w;
            y[4] = (__bf16)x1.x; y[5] = (__bf16)x1.y; y[6] = (__bf16)x1.z; y[7] = (__bf16)x1.w;
            ((bf16x8*)kp)[g] = y;
        }
    } else if (bid < 2560) {
        int vb = bid - 2048;                // 0..511: one (b, kb) tile
        int b = vb >> 7, kb = vb & 127;
        const float4* src = (const float4*)(v + (size_t)(b * N_ + kb * 32) * D_);
#pragma unroll
        for (int rep = 0; rep < 4; ++rep) {
            int i = rep * 256 + tid;
            int row = i >> 5, c4 = i & 31;
            float4 x = src[row * 32 + c4];
            float* dst = &vl[row * 129 + c4 * 4];
            dst[0] = x.x; dst[1] = x.y; dst[2] = x.z; dst[3] = x.w;
        }
        __syncthreads();
#pragma unroll
        for (int rep = 0; rep < 2; ++rep) {
            int ci = rep * 256 + tid;       // 0..511
            int ds = ci >> 6, ln = ci & 63;
            int quad = ln >> 4, l15 = ln & 15;
            bf16x8 y;
#pragma unroll
            for (int j = 0; j < 8; ++j)
                y[j] = (__bf16)vl[(quad * 8 + j) * 129 + ds * 16 + l15];
            ((bf16x8*)vp)[(((size_t)(b * 128 + kb) * 8) + ds) * 64 + ln] = y;
        }
    } else {
        // zero l: 16384 floats, 256 threads x 16 float4
        f32x4* lz = (f32x4*)l;
#pragma unroll
        for (int rep = 0; rep < 16; ++rep)
            lz[rep * 256 + tid] = (f32x4){0.f, 0.f, 0.f, 0.f};
    }
}

// ---------------------------------------------------------------------------
// Kernel B: column stats with LDS-shared Q tiles (R9/R10-proven), QSEG=8,
// grid 1024 blocks of 256 -> 4 blocks/CU, 16 waves/CU.
// ---------------------------------------------------------------------------
__global__ __launch_bounds__(256, 4) void stats_kernel(
    const __bf16* __restrict__ qp, const __bf16* __restrict__ kp,
    float* __restrict__ l)
{
    __shared__ __bf16 lds[2][16 * 512];   // 2 x 16 KiB

    int idx = blockIdx.x;
    int qseg = idx & (QSEG - 1);
    int kb4 = (idx >> 3) & 31;
    int b = idx >> 8;
    int w = threadIdx.x >> 6;
    int lane = threadIdx.x & 63;
    int quad = lane >> 4, l15 = lane & 15;
    int kb = kb4 * 4 + w;

    const bf16x8* kc = (const bf16x8*)kp;
    const bf16x8* qc8 = (const bf16x8*)qp;

    bf16x8 af[2][4];
#pragma unroll
    for (int ab = 0; ab < 2; ++ab)
#pragma unroll
        for (int f = 0; f < 4; ++f)
            af[ab][f] = kc[(((size_t)(b * 128 + kb) * 8) + f * 2 + ab) * 64 + lane];

    int qs0 = qseg * 32;                  // 32 q-steps per segment, 8 iters of 4
    bf16x8 st[4];
#pragma unroll
    for (int f = 0; f < 4; ++f)
        st[f] = qc8[((size_t)(b * 256 + qs0 + w) * 4 + f) * 64 + lane];

    float ps[8];
#pragma unroll
    for (int s = 0; s < 8; ++s) ps[s] = 0.f;

    for (int t = 0; t < 8; ++t) {
        __bf16* buf = &lds[t & 1][0];
#pragma unroll
        for (int f = 0; f < 4; ++f)
            *(bf16x8*)(buf + (w * 4 + f) * 512 + lane * 8) = st[f];
        int tn = (t + 1 < 8) ? t + 1 : t;
#pragma unroll
        for (int f = 0; f < 4; ++f)
            st[f] = qc8[((size_t)(b * 256 + qs0 + tn * 4 + w) * 4 + f) * 64 + lane];
        __syncthreads();                  // tile t visible to all waves
#pragma unroll
        for (int j = 0; j < 4; ++j) {
            bf16x8 qf[4];
#pragma unroll
            for (int f = 0; f < 4; ++f)
                qf[f] = *(const bf16x8*)(buf + (j * 4 + f) * 512 + lane * 8);
#pragma unroll
            for (int ab = 0; ab < 2; ++ab) {
                f32x4 acc = {0.f, 0.f, 0.f, 0.f};
#pragma unroll
                for (int f = 0; f < 4; ++f)
                    acc = __builtin_amdgcn_mfma_f32_16x16x32_bf16(af[ab][f], qf[f], acc, 0, 0, 0);
#pragma unroll
                for (int r = 0; r < 4; ++r)
                    ps[ab * 4 + r] += __builtin_amdgcn_exp2f(acc[r]);
            }
        }
    }
#pragma unroll
    for (int m = 1; m <= 8; m <<= 1)
#pragma unroll
        for (int s = 0; s < 8; ++s)
            ps[s] += __shfl_xor(ps[s], m, 64);
    if (l15 == 0) {
        float* dst = l + (size_t)b * N_ + kb * 32 + quad * 8;
#pragma unroll
        for (int ab = 0; ab < 2; ++ab)
#pragma unroll
            for (int r = 0; r < 4; ++r)
                atomicAdd(dst + ab * 4 + r, ps[ab * 4 + r]);
    }
}

// ---------------------------------------------------------------------------
// Kernel C2: Vp chunk (b,kb,ds,lane) *= 1/l[b][kb*32 + quad*8 .. +8]
// ---------------------------------------------------------------------------
__global__ __launch_bounds__(256) void scalev_kernel(
    const float* __restrict__ l, __bf16* __restrict__ vp)
{
    int i = blockIdx.x * 256 + threadIdx.x;  // chunk index, 262144 total
    int lane = i & 63;
    int kb = (i >> 9) & 127;
    int b = i >> 16;
    int quad = lane >> 4;
    int k0 = kb * 32 + quad * 8;
    const float* lp = l + (size_t)b * N_ + k0;
    float4 a = *(const float4*)lp;
    float4 c = *(const float4*)(lp + 4);
    float r0 = __builtin_amdgcn_rcpf(a.x), r1 = __builtin_amdgcn_rcpf(a.y);
    float r2 = __builtin_amdgcn_rcpf(a.z), r3 = __builtin_amdgcn_rcpf(a.w);
    float r4 = __builtin_amdgcn_rcpf(c.x), r5 = __builtin_amdgcn_rcpf(c.y);
    float r6 = __builtin_amdgcn_rcpf(c.z), r7 = __builtin_amdgcn_rcpf(c.w);
    bf16x8 v = ((const bf16x8*)vp)[i];
    bf16x8 o;
    o[0] = (__bf16)((float)v[0] * r0); o[1] = (__bf16)((float)v[1] * r1);
    o[2] = (__bf16)((float)v[2] * r2); o[3] = (__bf16)((float)v[3] * r3);
    o[4] = (__bf16)((float)v[4] * r4); o[5] = (__bf16)((float)v[5] * r5);
    o[6] = (__bf16)((float)v[6] * r6); o[7] = (__bf16)((float)v[7] * r7);
    ((bf16x8*)vp)[i] = o;
}

// ---------------------------------------------------------------------------
// Kernel D: attention, R9-proven structure, KSEG=8 -> grid 1024 blocks of 256
// (4 blocks/CU, 16 waves/CU). Per-iter work per wave UNCHANGED (16 b128 reads,
// 32 MFMA, single barrier); only seg count and fp16 partial output changed.
// ---------------------------------------------------------------------------
__global__ __launch_bounds__(256, 4) void attn_kernel(
    const __bf16* __restrict__ qp, const __bf16* __restrict__ kp,
    const __bf16* __restrict__ vp, _Float16* __restrict__ part)
{
    __shared__ __bf16 lds[2][16 * 512];   // 2 x 16 KiB: chunks 0-7 K, 8-15 V

    int idx = blockIdx.x;
    int seg = idx & (KSEG - 1);
    int qtile = (idx >> 3) & 31;          // 32 tiles of 128 q
    int b = idx >> 8;
    int w = threadIdx.x >> 6;
    int lane = threadIdx.x & 63;
    int quad = lane >> 4, l15 = lane & 15;

    const bf16x8* qc8 = (const bf16x8*)qp;
    const bf16x8* kc = (const bf16x8*)kp;
    const bf16x8* vc = (const bf16x8*)vp;

    int q0w = qtile * 128 + w * 32;       // this wave's 32 q
    int qstep0 = qtile * 8 + w * 2;
    bf16x8 bq[2][4];
#pragma unroll
    for (int s = 0; s < 2; ++s)
#pragma unroll
        for (int f = 0; f < 4; ++f)
            bq[s][f] = qc8[((size_t)(b * 256 + qstep0 + s) * 4 + f) * 64 + lane];

    f32x4 oacc[2][8];
#pragma unroll
    for (int s = 0; s < 2; ++s)
#pragma unroll
        for (int d = 0; d < 8; ++d) oacc[s][d] = (f32x4){0.f, 0.f, 0.f, 0.f};

    int kb0 = seg * 16;                   // 16 kb tiles per segment
    bf16x8 st[4];
#pragma unroll
    for (int i = 0; i < 4; ++i) {
        int c = w * 4 + i;
        st[i] = (c < 8) ? kc[(((size_t)(b * 128 + kb0) * 8) + c) * 64 + lane]
                        : vc[(((size_t)(b * 128 + kb0) * 8) + (c - 8)) * 64 + lane];
    }

    for (int t = 0; t < 16; ++t) {
        __bf16* buf = &lds[t & 1][0];
#pragma unroll
        for (int i = 0; i < 4; ++i)
            *(bf16x8*)(buf + (w * 4 + i) * 512 + lane * 8) = st[i];
        int kbn = kb0 + ((t + 1 < 16) ? t + 1 : t);
#pragma unroll
        for (int i = 0; i < 4; ++i) {
            int c = w * 4 + i;
            st[i] = (c < 8) ? kc[(((size_t)(b * 128 + kbn) * 8) + c) * 64 + lane]
                            : vc[(((size_t)(b * 128 + kbn) * 8) + (c - 8)) * 64 + lane];
        }
        __syncthreads();                  // tile t visible

        bf16x8 akA[4], akB[4];
#pragma unroll
        for (int f = 0; f < 4; ++f) {
            akA[f] = *(const bf16x8*)(buf + (f * 2 + 0) * 512 + lane * 8);
            akB[f] = *(const bf16x8*)(buf + (f * 2 + 1) * 512 + lane * 8);
        }
        bf16x8 pb[2];
#pragma unroll
        for (int s = 0; s < 2; ++s) {
            f32x4 accA = {0.f, 0.f, 0.f, 0.f};
            f32x4 accB = {0.f, 0.f, 0.f, 0.f};
#pragma unroll
            for (int f = 0; f < 4; ++f) {
                accA = __builtin_amdgcn_mfma_f32_16x16x32_bf16(akA[f], bq[s][f], accA, 0, 0, 0);
                accB = __builtin_amdgcn_mfma_f32_16x16x32_bf16(akB[f], bq[s][f], accB, 0, 0, 0);
            }
            bf16x8 p;
            p[0] = (__bf16)__builtin_amdgcn_exp2f(accA[0]);
            p[1] = (__bf16)__builtin_amdgcn_exp2f(accA[1]);
            p[2] = (__bf16)__builtin_amdgcn_exp2f(accA[2]);
            p[3] = (__bf16)__builtin_amdgcn_exp2f(accA[3]);
            p[4] = (__bf16)__builtin_amdgcn_exp2f(accB[0]);
            p[5] = (__bf16)__builtin_amdgcn_exp2f(accB[1]);
            p[6] = (__bf16)__builtin_amdgcn_exp2f(accB[2]);
            p[7] = (__bf16)__builtin_amdgcn_exp2f(accB[3]);
            pb[s] = p;
        }
#pragma unroll
        for (int ds = 0; ds < 8; ++ds) {
            bf16x8 vf = *(const bf16x8*)(buf + (8 + ds) * 512 + lane * 8);
#pragma unroll
            for (int s = 0; s < 2; ++s)
                oacc[s][ds] = __builtin_amdgcn_mfma_f32_16x16x32_bf16(
                    vf, pb[s], oacc[s][ds], 0, 0, 0);
        }
    }

    // epilogue: fp16 partials; d = ds*16 + quad*4 + r, q = q0w + s*16 + l15
    _Float16* op = part + ((size_t)seg * B_ * N_ + (size_t)b * N_ + q0w) * D_;
#pragma unroll
    for (int s = 0; s < 2; ++s)
#pragma unroll
        for (int ds = 0; ds < 8; ++ds) {
            f16x4 h;
            h[0] = (_Float16)oacc[s][ds][0]; h[1] = (_Float16)oacc[s][ds][1];
            h[2] = (_Float16)oacc[s][ds][2]; h[3] = (_Float16)oacc[s][ds][3];
            *(f16x4*)(op + (size_t)(s * 16 + l15) * D_ + ds * 16 + quad * 4) = h;
        }
}

// ---------------------------------------------------------------------------
// Kernel E: out = sum of KSEG fp16 partial slices (fp32 accumulate)
// ---------------------------------------------------------------------------
__global__ __launch_bounds__(256) void reduce_kernel(
    const _Float16* __restrict__ part, float* __restrict__ out)
{
    int i = blockIdx.x * 256 + threadIdx.x;   // f16x4 group index, 524288 total
    const f16x4* p = (const f16x4*)part;
    f32x4 s = {0.f, 0.f, 0.f, 0.f};
#pragma unroll
    for (int sgi = 0; sgi < KSEG; ++sgi) {
        f16x4 t = p[(size_t)sgi * (B_ * N_ * D_ / 4) + i];
        s[0] += (float)t[0]; s[1] += (float)t[1];
        s[2] += (float)t[2]; s[3] += (float)t[3];
    }
    ((f32x4*)out)[i] = s;
}

extern "C" void kernel_launch(void* const* d_in, const int* in_sizes, int n_in,
                              void* d_out, int out_size, void* d_ws, size_t ws_size,
                              hipStream_t stream) {
    const float* q = (const float*)d_in[0];
    const float* k = (const float*)d_in[1];
    const float* v = (const float*)d_in[2];
    float* out = (float*)d_out;
    char* ws = (char*)d_ws;
    __bf16* qp = (__bf16*)(ws);
    __bf16* kp = (__bf16*)(ws + OFF_KP);
    __bf16* vp = (__bf16*)(ws + OFF_VP);
    float* l    = (float*)(ws + OFF_L);
    _Float16* part = (_Float16*)(ws + OFF_PART);

    hipLaunchKernelGGL(cvt_kernel, dim3(2561), dim3(256), 0, stream, q, k, v, qp, kp, vp, l);
    hipLaunchKernelGGL(stats_kernel, dim3(B_ * 32 * QSEG), dim3(256), 0, stream, qp, kp, l);
    hipLaunchKernelGGL(scalev_kernel, dim3(1024), dim3(256), 0, stream, l, vp);
    hipLaunchKernelGGL(attn_kernel, dim3(B_ * 32 * KSEG), dim3(256), 0, stream, qp, kp, vp, part);
    hipLaunchKernelGGL(reduce_kernel, dim3(B_ * N_ * D_ / 4 / 256), dim3(256), 0, stream, part, out);
}